// Round 4
// baseline (146.431 us; speedup 1.0000x reference)
//
#include <hip/hip_runtime.h>

#define NENT 100000
#define NREL 32
#define DIM  128
#define NB   2048

typedef short s8v __attribute__((ext_vector_type(8)));
typedef float f4v __attribute__((ext_vector_type(4)));

__device__ __forceinline__ unsigned short f2bf(float x){
  unsigned u = __float_as_uint(x);
  return (unsigned short)((u + 0x7fffu + ((u>>16)&1u)) >> 16);
}
__device__ __forceinline__ float leakyf(float x){ return x > 0.f ? x : 0.2f*x; }

// ---------------- prep: P[r]=A1_right@renorm(rel[r]); A1LT = A1_left^T; A2f = A2 bf16 MFMA frags
__global__ __launch_bounds__(128) void k_prep(const float* __restrict__ rel,
                                              const float* __restrict__ A1,
                                              const float* __restrict__ A2,
                                              float* __restrict__ Pg,
                                              float* __restrict__ A1LT,
                                              unsigned short* __restrict__ A2f){
  int blk = blockIdx.x, t = threadIdx.x;
  if (blk < 32){
    int r = blk;
    __shared__ float srn[128];
    __shared__ float red[2];
    float v = rel[r*128 + t];
    float ss = v*v;
    for (int m=1;m<64;m<<=1) ss += __shfl_xor(ss, m);
    if ((t&63)==0) red[t>>6] = ss;
    __syncthreads();
    float nrm = sqrtf(red[0]+red[1]);
    float f = fminf(1.f, 1.f/(nrm + 1e-7f));
    srn[t] = v*f;
    __syncthreads();
    const float4* ar = (const float4*)(A1 + t*256 + 128);
    float acc = 0.f;
#pragma unroll
    for (int k4=0;k4<32;k4++){
      float4 a = ar[k4];
      acc += a.x*srn[k4*4] + a.y*srn[k4*4+1] + a.z*srn[k4*4+2] + a.w*srn[k4*4+3];
    }
    Pg[r*128 + t] = acc;
  } else if (blk < 64){
    // A2 bf16 fragment prepack: fid=(dt*4+kc)*64+lane -> 8 bf16 along k
    int bb = blk - 32;
    int fid = bb*64 + (t>>1);
    int half = t&1;
    int lane = fid & 63, kc = (fid>>6)&3, dt = fid>>8;
    int d = dt*16 + (lane&15);
    int kb = kc*32 + ((lane>>4)&3)*8 + half*4;
#pragma unroll
    for (int i=0;i<4;i++)
      A2f[fid*8 + half*4 + i] = f2bf(A2[d*128 + kb + i]);
  } else {
    int kb = blk - 64;          // 0..127
    A1LT[kb*128 + t] = A1[t*256 + kb];
  }
}

// ---------------- per-entity renorm scale table
__global__ __launch_bounds__(256) void k_scale(const float* __restrict__ ent,
                                               float* __restrict__ scaleTab){
  int row = blockIdx.x*4 + (threadIdx.x>>6);
  if (row >= NENT) return;
  int l = threadIdx.x & 63;
  float2 v = *(const float2*)(ent + (size_t)row*128 + 2*l);
  float ss = v.x*v.x + v.y*v.y;
  for (int m=1;m<64;m<<=1) ss += __shfl_xor(ss, m);
  if (l==0) scaleTab[row] = fminf(1.f, 1.f/(sqrtf(ss) + 1e-7f));
}

// ---------------- gather indices, h, s1 (h also written to out[:,512:640])
__global__ __launch_bounds__(256) void k_gather(const int* __restrict__ eidx,
                                                const int* __restrict__ adjE,
                                                const int* __restrict__ adjR,
                                                const float* __restrict__ ent,
                                                const float* __restrict__ scaleTab,
                                                int* __restrict__ E1, int* __restrict__ R0,
                                                int* __restrict__ E2, int* __restrict__ R1,
                                                float* __restrict__ Hb, float* __restrict__ S1,
                                                float* __restrict__ out){
  int b = blockIdx.x, t = threadIdx.x, l = t&63, w = t>>6;
  __shared__ int sE1[16];
  __shared__ float sPart[4][128];
  int idx = eidx[b];
  if (t < 16){
    int e = adjE[idx*16 + t];
    sE1[t] = e; E1[b*16+t] = e;
    R0[b*16+t] = adjR[idx*16 + t];
  }
  __syncthreads();
  {
    int e1 = sE1[t>>4];
    E2[b*256+t] = adjE[e1*16 + (t&15)];
    R1[b*256+t] = adjR[e1*16 + (t&15)];
  }
  float2 acc = {0.f, 0.f};
#pragma unroll
  for (int i=0;i<4;i++){
    int row = w*4 + i; int e = sE1[row];
    float sc = scaleTab[e];
    float2 v = *(const float2*)(ent + (size_t)e*128 + 2*l);
    acc.x += sc*v.x; acc.y += sc*v.y;
  }
  sPart[w][2*l] = acc.x; sPart[w][2*l+1] = acc.y;
  if (w == 0){
    float sc = scaleTab[idx];
    float2 v = *(const float2*)(ent + (size_t)idx*128 + 2*l);
    float2 hv = { sc*v.x, sc*v.y };
    *(float2*)(Hb + b*128 + 2*l) = hv;
    *(float2*)(out + (size_t)b*640 + 512 + 2*l) = hv;
  }
  __syncthreads();
  if (t < 128) S1[b*128 + t] = sPart[0][t]+sPart[1][t]+sPart[2][t]+sPart[3][t];
}

// ---------------- scores: c=A1_left@anchor; a1=relu(c+P[r]) (bf16); a2=relu(A2@a1) via MFMA; sigmoid(A3.a2)
__global__ __launch_bounds__(256) void k_scores(const float* __restrict__ Hb,
                                                const float* __restrict__ S1,
                                                const float* __restrict__ A1LT,
                                                const float* __restrict__ Pg,
                                                const unsigned short* __restrict__ A2f,
                                                const float* __restrict__ A3,
                                                float* __restrict__ SC){
  int b = blockIdx.x, t = threadIdx.x, l = t&63, w = t>>6;
  __shared__ float sHS[2][128];
  __shared__ float sC[2][128];
  __shared__ float sP[32][130];
  __shared__ __align__(16) unsigned short sA1b[64*128];   // a1^T [c][k] bf16, xor-swizzled

  if (t < 128) sHS[0][t] = Hb[b*128 + t];
  else         sHS[1][t-128] = S1[b*128 + (t-128)];
#pragma unroll
  for (int i=0;i<16;i++){ int id = i*256 + t; sP[id>>7][id&127] = Pg[id]; }
  __syncthreads();

  { // c0/c1 matvec: thread (i=t>>7, d=t&127)
    int i = t>>7, d = t&127;
    float acc = 0.f;
#pragma unroll 4
    for (int k=0;k<128;k++) acc += A1LT[k*128 + d] * sHS[i][k];
    sC[i][d] = acc;
  }
  __syncthreads();

  { // build a1 bf16, swizzled
    int c = t & 63, i = c>>5, r = c&31, base = t>>6;
#pragma unroll
    for (int ch=0; ch<16; ch++){
      int kp = base*16 + ch;                       // k-pair index 0..63
      float2 cc = *(const float2*)&sC[i][2*kp];
      float2 pp = *(const float2*)&sP[r][2*kp];
      float v0 = fmaxf(cc.x + pp.x, 0.f);
      float v1 = fmaxf(cc.y + pp.y, 0.f);
      unsigned pk = (unsigned)f2bf(v0) | ((unsigned)f2bf(v1) << 16);
      int byte = (c*256 + kp*4) ^ ((c&7)<<4);
      *(unsigned*)((char*)sA1b + byte) = pk;
    }
  }
  __syncthreads();

  { // MFMA GEMM: wave w owns c-tile c0=w*16; loop 8 d-tiles; fold A3 dot + sigmoid
    int c0 = w*16, cl = l & 15, kg = l >> 4;
    int c = c0 + cl;
    s8v bfrag[4];
#pragma unroll
    for (int kc=0;kc<4;kc++){
      int byte = (c*256 + kc*64 + kg*16) ^ ((c&7)<<4);
      bfrag[kc] = *(const s8v*)((const char*)sA1b + byte);
    }
    float sacc = 0.f;
#pragma unroll
    for (int dt=0; dt<8; dt++){
      f4v acc = {0.f,0.f,0.f,0.f};
#pragma unroll
      for (int kc=0;kc<4;kc++){
        s8v af = *(const s8v*)(A2f + ((size_t)((dt*4+kc)*64 + l))*8);
        acc = __builtin_amdgcn_mfma_f32_16x16x32_bf16(af, bfrag[kc], acc, 0, 0, 0);
      }
      float4 a3v = *(const float4*)(A3 + dt*16 + kg*4);
      sacc += fmaxf(acc[0],0.f)*a3v.x + fmaxf(acc[1],0.f)*a3v.y
            + fmaxf(acc[2],0.f)*a3v.z + fmaxf(acc[3],0.f)*a3v.w;
    }
    sacc += __shfl_xor(sacc, 16);
    sacc += __shfl_xor(sacc, 32);
    if (l < 16) SC[b*64 + c0 + l] = 1.f/(1.f + __expf(-sacc));
  }
}

// ---------------- softmax over neighbors (scores are lookups) + weighted renormed gathers -> SV
__global__ __launch_bounds__(256) void k_soft_sv(const int* __restrict__ E1,
                                                 const int* __restrict__ R0,
                                                 const int* __restrict__ E2,
                                                 const int* __restrict__ R1,
                                                 const float* __restrict__ SC,
                                                 const float* __restrict__ ent,
                                                 const float* __restrict__ scaleTab,
                                                 float* __restrict__ SV){
  int b = blockIdx.x, t = threadIdx.x, l = t&63, w = t>>6;
  __shared__ float sSC[64];
  __shared__ float sW0[16];
  __shared__ float sW1[256];
  __shared__ float sRed[4];
  __shared__ float sPart[4][128];
  if (t < 64) sSC[t] = SC[b*64 + t];
  __syncthreads();
  float ev = __expf(sSC[32 + R1[b*256 + t]]);
  float ssum = ev;
  for (int m=1;m<64;m<<=1) ssum += __shfl_xor(ssum, m);
  if (l==0) sRed[w] = ssum;
  if (t < 16){
    float e0 = __expf(sSC[R0[b*16 + t]]);
    float s0 = e0;
    for (int m=1;m<16;m<<=1) s0 += __shfl_xor(s0, m, 16);
    sW0[t] = e0/s0;
  }
  __syncthreads();
  float tot = sRed[0]+sRed[1]+sRed[2]+sRed[3];
  sW1[t] = ev / tot;
  __syncthreads();

  float2 a0 = {0.f,0.f};
#pragma unroll
  for (int i=0;i<4;i++){
    int row = w*4 + i; int e = E1[b*16 + row];
    float f = scaleTab[e] * sW0[row];
    float2 v = *(const float2*)(ent + (size_t)e*128 + 2*l);
    a0.x += f*v.x; a0.y += f*v.y;
  }
  float2 a1 = {0.f,0.f};
#pragma unroll 4
  for (int i=0;i<64;i++){
    int row = w*64 + i; int e = E2[b*256 + row];
    float f = scaleTab[e] * sW1[row];
    float2 v = *(const float2*)(ent + (size_t)e*128 + 2*l);
    a1.x += f*v.x; a1.y += f*v.y;
  }
  *(float2*)&sPart[w][2*l] = a0;
  __syncthreads();
  if (t < 128) SV[((size_t)b*2 + 0)*128 + t] = sPart[0][t]+sPart[1][t]+sPart[2][t]+sPart[3][t];
  __syncthreads();
  *(float2*)&sPart[w][2*l] = a1;
  __syncthreads();
  if (t < 128) SV[((size_t)b*2 + 1)*128 + t] = sPart[0][t]+sPart[1][t]+sPart[2][t]+sPart[3][t];
}

// ---------------- V = leaky(Wx@sv + b); e = leaky((a+v)W1^T+b1)+leaky((a*v)W2^T+b2); 16 b-rows/block
__global__ __launch_bounds__(256) void k_vagg(const float* __restrict__ SV,
                                              const float* __restrict__ Hb,
                                              const float* __restrict__ S1,
                                              const float* __restrict__ Wxw,
                                              const float* __restrict__ Wxb,
                                              const float* __restrict__ W1w,
                                              const float* __restrict__ W1b,
                                              const float* __restrict__ W2w,
                                              const float* __restrict__ W2b,
                                              float* __restrict__ out){
  int b0 = blockIdx.x * 16;
  int iter = blockIdx.y;
  int t = threadIdx.x;
  __shared__ float sSV[16][128];
  __shared__ float sA[16][128];
  __shared__ float sV[16][256];
  const float* anc = iter ? S1 : Hb;
#pragma unroll
  for (int i=0;i<8;i++){
    int id = i*256 + t; int bl = id>>7, d = id&127;
    sSV[bl][d] = SV[((size_t)(b0+bl)*2 + iter)*128 + d];
    sA[bl][d]  = anc[(size_t)(b0+bl)*128 + d];
  }
  __syncthreads();
  { // V
    int head = t>>7, e = t&127;
    const float4* wrow = (const float4*)(Wxw + ((size_t)((iter*2)+head)*128 + e)*128);
    float bias = Wxb[((iter*2)+head)*128 + e];
    float acc[16];
#pragma unroll
    for (int bl=0;bl<16;bl++) acc[bl] = bias;
    for (int k4=0;k4<32;k4++){
      float4 wv = wrow[k4];
#pragma unroll
      for (int bl=0;bl<16;bl++){
        float4 sv = *(const float4*)&sSV[bl][k4*4];
        acc[bl] += wv.x*sv.x + wv.y*sv.y + wv.z*sv.z + wv.w*sv.w;
      }
    }
#pragma unroll
    for (int bl=0;bl<16;bl++) sV[bl][t] = leakyf(acc[bl]);
  }
  __syncthreads();
  { // agg
    const float4* w1r = (const float4*)(W1w + (size_t)t*256);
    const float4* w2r = (const float4*)(W2w + (size_t)t*256);
    float b1 = W1b[t], b2 = W2b[t];
    float acc1[16], acc2[16];
#pragma unroll
    for (int bl=0;bl<16;bl++){ acc1[bl]=b1; acc2[bl]=b2; }
    for (int k4=0;k4<64;k4++){
      float4 w1v = w1r[k4], w2v = w2r[k4];
      int ia = (k4*4) & 127;
#pragma unroll
      for (int bl=0;bl<16;bl++){
        float4 av = *(const float4*)&sA[bl][ia];
        float4 vv = *(const float4*)&sV[bl][k4*4];
        acc1[bl] += (av.x+vv.x)*w1v.x + (av.y+vv.y)*w1v.y + (av.z+vv.z)*w1v.z + (av.w+vv.w)*w1v.w;
        acc2[bl] += (av.x*vv.x)*w2v.x + (av.y*vv.y)*w2v.y + (av.z*vv.z)*w2v.z + (av.w*vv.w)*w2v.w;
      }
    }
    int obase = iter ? 0 : 256;
#pragma unroll
    for (int bl=0;bl<16;bl++){
      out[(size_t)(b0+bl)*640 + obase + t] = leakyf(acc1[bl]) + leakyf(acc2[bl]);
    }
  }
}

extern "C" void kernel_launch(void* const* d_in, const int* in_sizes, int n_in,
                              void* d_out, int out_size, void* d_ws, size_t ws_size,
                              hipStream_t stream) {
  const int*   eidx = (const int*)d_in[0];
  const int*   adjE = (const int*)d_in[1];
  const int*   adjR = (const int*)d_in[2];
  const float* ent  = (const float*)d_in[3];
  const float* rel  = (const float*)d_in[4];
  const float* A1   = (const float*)d_in[5];
  const float* A2   = (const float*)d_in[6];
  const float* A3   = (const float*)d_in[7];
  const float* Wxw  = (const float*)d_in[8];
  const float* Wxb  = (const float*)d_in[9];
  const float* W1w  = (const float*)d_in[10];
  const float* W1b  = (const float*)d_in[11];
  const float* W2w  = (const float*)d_in[12];
  const float* W2b  = (const float*)d_in[13];
  float* out = (float*)d_out;

  char* wsb = (char*)d_ws;
  size_t off = 0;
  auto alloc = [&](size_t bytes)->char*{
    char* p = wsb + off; off += (bytes + 255) & ~(size_t)255; return p;
  };
  float* Pg   = (float*)alloc(NREL*DIM*4);
  float* A1LT = (float*)alloc(DIM*DIM*4);
  unsigned short* A2f = (unsigned short*)alloc(2048*8*2);
  float* scaleTab = (float*)alloc((size_t)NENT*4);
  float* Hb = (float*)alloc((size_t)NB*DIM*4);
  float* S1 = (float*)alloc((size_t)NB*DIM*4);
  float* SC = (float*)alloc((size_t)NB*64*4);
  float* SV = (float*)alloc((size_t)NB*2*DIM*4);
  int* E1 = (int*)alloc((size_t)NB*16*4);
  int* R0 = (int*)alloc((size_t)NB*16*4);
  int* E2 = (int*)alloc((size_t)NB*256*4);
  int* R1 = (int*)alloc((size_t)NB*256*4);

  k_prep <<<dim3(192),   dim3(128), 0, stream>>>(rel, A1, A2, Pg, A1LT, A2f);
  k_scale<<<dim3(25000), dim3(256), 0, stream>>>(ent, scaleTab);
  k_gather<<<dim3(NB),   dim3(256), 0, stream>>>(eidx, adjE, adjR, ent, scaleTab,
                                                 E1, R0, E2, R1, Hb, S1, out);
  k_scores<<<dim3(NB),   dim3(256), 0, stream>>>(Hb, S1, A1LT, Pg, A2f, A3, SC);
  k_soft_sv<<<dim3(NB),  dim3(256), 0, stream>>>(E1, R0, E2, R1, SC, ent, scaleTab, SV);
  k_vagg <<<dim3(NB/16, 2), dim3(256), 0, stream>>>(SV, Hb, S1, Wxw, Wxb,
                                                    W1w, W1b, W2w, W2b, out);
}

// Round 5
// 117.176 us; speedup vs baseline: 1.2497x; 1.2497x over previous
//
#include <hip/hip_runtime.h>

#define NENT 100000
#define NREL 32
#define DIM  128
#define NB   2048

typedef short s8v __attribute__((ext_vector_type(8)));
typedef float f4v __attribute__((ext_vector_type(4)));

__device__ __forceinline__ unsigned short f2bf(float x){
  unsigned u = __float_as_uint(x);
  return (unsigned short)((u + 0x7fffu + ((u>>16)&1u)) >> 16);
}
__device__ __forceinline__ float bf2f(unsigned short u){
  return __uint_as_float(((unsigned)u) << 16);
}
__device__ __forceinline__ float leakyf(float x){ return x > 0.f ? x : 0.2f*x; }

// ---------------- prep: P[r]; A1LT; A2 frags; Wx/W1/W2 bf16 B-fragment prepack
__global__ __launch_bounds__(128) void k_prep(const float* __restrict__ rel,
                                              const float* __restrict__ A1,
                                              const float* __restrict__ A2,
                                              const float* __restrict__ Wxw,
                                              const float* __restrict__ W1w,
                                              const float* __restrict__ W2w,
                                              float* __restrict__ Pg,
                                              float* __restrict__ A1LT,
                                              unsigned short* __restrict__ A2f,
                                              unsigned short* __restrict__ WxF,
                                              unsigned short* __restrict__ W1F,
                                              unsigned short* __restrict__ W2F){
  int blk = blockIdx.x, t = threadIdx.x;
  if (blk < 32){
    int r = blk;
    __shared__ float srn[128];
    __shared__ float red[2];
    float v = rel[r*128 + t];
    float ss = v*v;
    for (int m=1;m<64;m<<=1) ss += __shfl_xor(ss, m);
    if ((t&63)==0) red[t>>6] = ss;
    __syncthreads();
    float nrm = sqrtf(red[0]+red[1]);
    float f = fminf(1.f, 1.f/(nrm + 1e-7f));
    srn[t] = v*f;
    __syncthreads();
    const float4* ar = (const float4*)(A1 + t*256 + 128);
    float acc = 0.f;
#pragma unroll
    for (int k4=0;k4<32;k4++){
      float4 a = ar[k4];
      acc += a.x*srn[k4*4] + a.y*srn[k4*4+1] + a.z*srn[k4*4+2] + a.w*srn[k4*4+3];
    }
    Pg[r*128 + t] = acc;
  } else if (blk < 64){
    // A2 bf16 fragment prepack: fid=(dt*4+kc)*64+lane -> 8 bf16 along k
    int bb = blk - 32;
    int fid = bb*64 + (t>>1);
    int half = t&1;
    int lane = fid & 63, kc = (fid>>6)&3, dt = fid>>8;
    int d = dt*16 + (lane&15);
    int kb = kc*32 + ((lane>>4)&3)*8 + half*4;
#pragma unroll
    for (int i=0;i<4;i++)
      A2f[fid*8 + half*4 + i] = f2bf(A2[d*128 + kb + i]);
  } else if (blk < 192){
    int kb = blk - 64;          // 0..127
    A1LT[kb*128 + t] = A1[t*256 + kb];
  } else if (blk < 256){
    // WxF: fid = ((iter*16+nt)*4+kc)*64+l ; value = Wxw[iter, n>>7, n&127, k+j]
    int fid = (blk-192)*128 + t;
    int l = fid&63, kc = (fid>>6)&3, nt = (fid>>8)&15, iter = (fid>>12)&1;
    int n = nt*16 + (l&15);
    int k = kc*32 + ((l>>4)&3)*8;
    const float* src = Wxw + ((size_t)((iter*2 + (n>>7))*128 + (n&127)))*128 + k;
#pragma unroll
    for (int j=0;j<8;j++) WxF[(size_t)fid*8 + j] = f2bf(src[j]);
  } else if (blk < 320){
    // W1F: fid = (nt*8+kc)*64+l ; value = W1w[n*256 + k+j]
    int fid = (blk-256)*128 + t;
    int l = fid&63, kc = (fid>>6)&7, nt = (fid>>9)&15;
    int n = nt*16 + (l&15);
    int k = kc*32 + ((l>>4)&3)*8;
#pragma unroll
    for (int j=0;j<8;j++) W1F[(size_t)fid*8 + j] = f2bf(W1w[(size_t)n*256 + k + j]);
  } else {
    int fid = (blk-320)*128 + t;
    int l = fid&63, kc = (fid>>6)&7, nt = (fid>>9)&15;
    int n = nt*16 + (l&15);
    int k = kc*32 + ((l>>4)&3)*8;
#pragma unroll
    for (int j=0;j<8;j++) W2F[(size_t)fid*8 + j] = f2bf(W2w[(size_t)n*256 + k + j]);
  }
}

// ---------------- per-entity renorm scale table
__global__ __launch_bounds__(256) void k_scale(const float* __restrict__ ent,
                                               float* __restrict__ scaleTab){
  int row = blockIdx.x*4 + (threadIdx.x>>6);
  if (row >= NENT) return;
  int l = threadIdx.x & 63;
  float2 v = *(const float2*)(ent + (size_t)row*128 + 2*l);
  float ss = v.x*v.x + v.y*v.y;
  for (int m=1;m<64;m<<=1) ss += __shfl_xor(ss, m);
  if (l==0) scaleTab[row] = fminf(1.f, 1.f/(sqrtf(ss) + 1e-7f));
}

// ---------------- gather indices, h, s1 (h also written to out[:,512:640])
__global__ __launch_bounds__(256) void k_gather(const int* __restrict__ eidx,
                                                const int* __restrict__ adjE,
                                                const int* __restrict__ adjR,
                                                const float* __restrict__ ent,
                                                const float* __restrict__ scaleTab,
                                                int* __restrict__ E1, int* __restrict__ R0,
                                                int* __restrict__ E2, int* __restrict__ R1,
                                                float* __restrict__ Hb, float* __restrict__ S1,
                                                float* __restrict__ out){
  int b = blockIdx.x, t = threadIdx.x, l = t&63, w = t>>6;
  __shared__ int sE1[16];
  __shared__ float sPart[4][128];
  int idx = eidx[b];
  if (t < 16){
    int e = adjE[idx*16 + t];
    sE1[t] = e; E1[b*16+t] = e;
    R0[b*16+t] = adjR[idx*16 + t];
  }
  __syncthreads();
  {
    int e1 = sE1[t>>4];
    E2[b*256+t] = adjE[e1*16 + (t&15)];
    R1[b*256+t] = adjR[e1*16 + (t&15)];
  }
  float2 acc = {0.f, 0.f};
#pragma unroll
  for (int i=0;i<4;i++){
    int row = w*4 + i; int e = sE1[row];
    float sc = scaleTab[e];
    float2 v = *(const float2*)(ent + (size_t)e*128 + 2*l);
    acc.x += sc*v.x; acc.y += sc*v.y;
  }
  sPart[w][2*l] = acc.x; sPart[w][2*l+1] = acc.y;
  if (w == 0){
    float sc = scaleTab[idx];
    float2 v = *(const float2*)(ent + (size_t)idx*128 + 2*l);
    float2 hv = { sc*v.x, sc*v.y };
    *(float2*)(Hb + b*128 + 2*l) = hv;
    *(float2*)(out + (size_t)b*640 + 512 + 2*l) = hv;
  }
  __syncthreads();
  if (t < 128) S1[b*128 + t] = sPart[0][t]+sPart[1][t]+sPart[2][t]+sPart[3][t];
}

// ---------------- scores: c=A1_left@anchor; a1=relu(c+P[r]) (bf16); a2=relu(A2@a1) via MFMA; sigmoid(A3.a2)
__global__ __launch_bounds__(256) void k_scores(const float* __restrict__ Hb,
                                                const float* __restrict__ S1,
                                                const float* __restrict__ A1LT,
                                                const float* __restrict__ Pg,
                                                const unsigned short* __restrict__ A2f,
                                                const float* __restrict__ A3,
                                                float* __restrict__ SC){
  int b = blockIdx.x, t = threadIdx.x, l = t&63, w = t>>6;
  __shared__ float sHS[2][128];
  __shared__ float sC[2][128];
  __shared__ float sP[32][130];
  __shared__ __align__(16) unsigned short sA1b[64*128];   // a1^T [c][k] bf16, xor-swizzled

  if (t < 128) sHS[0][t] = Hb[b*128 + t];
  else         sHS[1][t-128] = S1[b*128 + (t-128)];
#pragma unroll
  for (int i=0;i<16;i++){ int id = i*256 + t; sP[id>>7][id&127] = Pg[id]; }
  __syncthreads();

  { // c0/c1 matvec: thread (i=t>>7, d=t&127)
    int i = t>>7, d = t&127;
    float acc = 0.f;
#pragma unroll 4
    for (int k=0;k<128;k++) acc += A1LT[k*128 + d] * sHS[i][k];
    sC[i][d] = acc;
  }
  __syncthreads();

  { // build a1 bf16, swizzled
    int c = t & 63, i = c>>5, r = c&31, base = t>>6;
#pragma unroll
    for (int ch=0; ch<16; ch++){
      int kp = base*16 + ch;                       // k-pair index 0..63
      float2 cc = *(const float2*)&sC[i][2*kp];
      float2 pp = *(const float2*)&sP[r][2*kp];
      float v0 = fmaxf(cc.x + pp.x, 0.f);
      float v1 = fmaxf(cc.y + pp.y, 0.f);
      unsigned pk = (unsigned)f2bf(v0) | ((unsigned)f2bf(v1) << 16);
      int byte = (c*256 + kp*4) ^ ((c&7)<<4);
      *(unsigned*)((char*)sA1b + byte) = pk;
    }
  }
  __syncthreads();

  { // MFMA GEMM: wave w owns c-tile c0=w*16; loop 8 d-tiles; fold A3 dot + sigmoid
    int c0 = w*16, cl = l & 15, kg = l >> 4;
    int c = c0 + cl;
    s8v bfrag[4];
#pragma unroll
    for (int kc=0;kc<4;kc++){
      int byte = (c*256 + kc*64 + kg*16) ^ ((c&7)<<4);
      bfrag[kc] = *(const s8v*)((const char*)sA1b + byte);
    }
    float sacc = 0.f;
#pragma unroll
    for (int dt=0; dt<8; dt++){
      f4v acc = {0.f,0.f,0.f,0.f};
#pragma unroll
      for (int kc=0;kc<4;kc++){
        s8v af = *(const s8v*)(A2f + ((size_t)((dt*4+kc)*64 + l))*8);
        acc = __builtin_amdgcn_mfma_f32_16x16x32_bf16(af, bfrag[kc], acc, 0, 0, 0);
      }
      float4 a3v = *(const float4*)(A3 + dt*16 + kg*4);
      sacc += fmaxf(acc[0],0.f)*a3v.x + fmaxf(acc[1],0.f)*a3v.y
            + fmaxf(acc[2],0.f)*a3v.z + fmaxf(acc[3],0.f)*a3v.w;
    }
    sacc += __shfl_xor(sacc, 16);
    sacc += __shfl_xor(sacc, 32);
    if (l < 16) SC[b*64 + c0 + l] = 1.f/(1.f + __expf(-sacc));
  }
}

// ---------------- softmax over neighbors (scores are lookups) + weighted renormed gathers -> SV
__global__ __launch_bounds__(256) void k_soft_sv(const int* __restrict__ E1,
                                                 const int* __restrict__ R0,
                                                 const int* __restrict__ E2,
                                                 const int* __restrict__ R1,
                                                 const float* __restrict__ SC,
                                                 const float* __restrict__ ent,
                                                 const float* __restrict__ scaleTab,
                                                 float* __restrict__ SV){
  int b = blockIdx.x, t = threadIdx.x, l = t&63, w = t>>6;
  __shared__ float sSC[64];
  __shared__ float sW0[16];
  __shared__ float sW1[256];
  __shared__ float sRed[4];
  __shared__ float sPart[4][128];
  if (t < 64) sSC[t] = SC[b*64 + t];
  __syncthreads();
  float ev = __expf(sSC[32 + R1[b*256 + t]]);
  float ssum = ev;
  for (int m=1;m<64;m<<=1) ssum += __shfl_xor(ssum, m);
  if (l==0) sRed[w] = ssum;
  if (t < 16){
    float e0 = __expf(sSC[R0[b*16 + t]]);
    float s0 = e0;
    for (int m=1;m<16;m<<=1) s0 += __shfl_xor(s0, m, 16);
    sW0[t] = e0/s0;
  }
  __syncthreads();
  float tot = sRed[0]+sRed[1]+sRed[2]+sRed[3];
  sW1[t] = ev / tot;
  __syncthreads();

  float2 a0 = {0.f,0.f};
#pragma unroll
  for (int i=0;i<4;i++){
    int row = w*4 + i; int e = E1[b*16 + row];
    float f = scaleTab[e] * sW0[row];
    float2 v = *(const float2*)(ent + (size_t)e*128 + 2*l);
    a0.x += f*v.x; a0.y += f*v.y;
  }
  float2 a1 = {0.f,0.f};
#pragma unroll 4
  for (int i=0;i<64;i++){
    int row = w*64 + i; int e = E2[b*256 + row];
    float f = scaleTab[e] * sW1[row];
    float2 v = *(const float2*)(ent + (size_t)e*128 + 2*l);
    a1.x += f*v.x; a1.y += f*v.y;
  }
  *(float2*)&sPart[w][2*l] = a0;
  __syncthreads();
  if (t < 128) SV[((size_t)b*2 + 0)*128 + t] = sPart[0][t]+sPart[1][t]+sPart[2][t]+sPart[3][t];
  __syncthreads();
  *(float2*)&sPart[w][2*l] = a1;
  __syncthreads();
  if (t < 128) SV[((size_t)b*2 + 1)*128 + t] = sPart[0][t]+sPart[1][t]+sPart[2][t]+sPart[3][t];
}

// ---------------- MFMA vagg: G1 V=leaky(Wx@sv+b) ; G2 e=leaky(W1@x1+b1)+leaky(W2@x2+b2)
// block: 32 batch rows, 4 waves (wm=row-half, wn=col-half)
__global__ __launch_bounds__(256) void k_vagg2(const float* __restrict__ SV,
                                               const float* __restrict__ Hb,
                                               const float* __restrict__ S1,
                                               const unsigned short* __restrict__ WxF,
                                               const float* __restrict__ Wxb,
                                               const unsigned short* __restrict__ W1F,
                                               const float* __restrict__ W1b,
                                               const unsigned short* __restrict__ W2F,
                                               const float* __restrict__ W2b,
                                               float* __restrict__ out){
  int b0 = blockIdx.x * 32;
  int iter = blockIdx.y;
  int t = threadIdx.x, l = t&63, w = t>>6;
  int wm = w>>1, wn = w&1;
  __shared__ __align__(16) unsigned short sSV[32*128];
  __shared__ __align__(16) unsigned short sA [32*128];
  __shared__ __align__(16) unsigned short sV [32*256];
  char* sSVb = (char*)sSV; char* sAb = (char*)sA; char* sVb = (char*)sV;

  const float* anc = iter ? S1 : Hb;
  { // stage SV + anchor as swizzled bf16 [32][128]
    int row = t>>3, c0 = (t&7)*16;
    const float* ps = SV + ((size_t)(b0+row)*2 + iter)*128 + c0;
    const float* pa = anc + (size_t)(b0+row)*128 + c0;
    int xo = (row&7)<<4;
#pragma unroll
    for (int c2=0;c2<8;c2++){
      float2 sv2 = *(const float2*)(ps + c2*2);
      float2 an2 = *(const float2*)(pa + c2*2);
      unsigned pv  = (unsigned)f2bf(sv2.x) | ((unsigned)f2bf(sv2.y)<<16);
      unsigned pan = (unsigned)f2bf(an2.x) | ((unsigned)f2bf(an2.y)<<16);
      int byte = (row*256 + c0*2 + c2*4) ^ xo;
      *(unsigned*)(sSVb + byte) = pv;
      *(unsigned*)(sAb  + byte) = pan;
    }
  }
  __syncthreads();

  int kl = l&15, kg = l>>4;
  { // G1: V[rows wm*16..+15][cols wn*128..+127]
    int rowg = wm*16 + kl;
    int xo = (rowg&7)<<4;
    s8v af[4];
#pragma unroll
    for (int kc=0;kc<4;kc++)
      af[kc] = *(const s8v*)(sSVb + ((rowg*256 + kc*64 + kg*16) ^ xo));
#pragma unroll
    for (int nt8=0;nt8<8;nt8++){
      int ntg = wn*8 + nt8;
      int n = ntg*16 + kl;
      float bias = Wxb[iter*256 + n];
      f4v acc = {bias,bias,bias,bias};
#pragma unroll
      for (int kc=0;kc<4;kc++){
        s8v bf = *(const s8v*)(WxF + ((size_t)(((iter*16 + ntg)*4 + kc)*64 + l))*8);
        acc = __builtin_amdgcn_mfma_f32_16x16x32_bf16(af[kc], bf, acc, 0, 0, 0);
      }
#pragma unroll
      for (int r=0;r<4;r++){
        int rowl = wm*16 + kg*4 + r;
        int byte = (rowl*512 + n*2) ^ ((rowl&7)<<4);
        *(unsigned short*)(sVb + byte) = f2bf(leakyf(acc[r]));
      }
    }
  }
  __syncthreads();
  { // G2
    int rowl = wm*16 + kl;
    int xo = (rowl&7)<<4;
    s8v x1f[8], x2f[8];
#pragma unroll
    for (int kc=0;kc<8;kc++){
      int k0 = kc*32 + kg*8;
      s8v vv = *(const s8v*)(sVb + ((rowl*512 + k0*2) ^ xo));
      s8v aa = *(const s8v*)(sAb + ((rowl*256 + (k0&127)*2) ^ xo));
#pragma unroll
      for (int j=0;j<8;j++){
        float vf = bf2f((unsigned short)vv[j]);
        float av = bf2f((unsigned short)aa[j]);
        x1f[kc][j] = (short)f2bf(av + vf);
        x2f[kc][j] = (short)f2bf(av * vf);
      }
    }
    int obase = iter ? 0 : 256;
#pragma unroll
    for (int nt8=0;nt8<8;nt8++){
      int ntg = wn*8 + nt8;
      int n = ntg*16 + kl;
      float bb1 = W1b[n], bb2 = W2b[n];
      f4v a1 = {bb1,bb1,bb1,bb1};
      f4v a2 = {bb2,bb2,bb2,bb2};
#pragma unroll
      for (int kc=0;kc<8;kc++){
        s8v wf1 = *(const s8v*)(W1F + ((size_t)((ntg*8 + kc)*64 + l))*8);
        a1 = __builtin_amdgcn_mfma_f32_16x16x32_bf16(x1f[kc], wf1, a1, 0, 0, 0);
      }
#pragma unroll
      for (int kc=0;kc<8;kc++){
        s8v wf2 = *(const s8v*)(W2F + ((size_t)((ntg*8 + kc)*64 + l))*8);
        a2 = __builtin_amdgcn_mfma_f32_16x16x32_bf16(x2f[kc], wf2, a2, 0, 0, 0);
      }
#pragma unroll
      for (int r=0;r<4;r++){
        int row = wm*16 + kg*4 + r;
        out[(size_t)(b0+row)*640 + obase + n] = leakyf(a1[r]) + leakyf(a2[r]);
      }
    }
  }
}

extern "C" void kernel_launch(void* const* d_in, const int* in_sizes, int n_in,
                              void* d_out, int out_size, void* d_ws, size_t ws_size,
                              hipStream_t stream) {
  const int*   eidx = (const int*)d_in[0];
  const int*   adjE = (const int*)d_in[1];
  const int*   adjR = (const int*)d_in[2];
  const float* ent  = (const float*)d_in[3];
  const float* rel  = (const float*)d_in[4];
  const float* A1   = (const float*)d_in[5];
  const float* A2   = (const float*)d_in[6];
  const float* A3   = (const float*)d_in[7];
  const float* Wxw  = (const float*)d_in[8];
  const float* Wxb  = (const float*)d_in[9];
  const float* W1w  = (const float*)d_in[10];
  const float* W1b  = (const float*)d_in[11];
  const float* W2w  = (const float*)d_in[12];
  const float* W2b  = (const float*)d_in[13];
  float* out = (float*)d_out;

  char* wsb = (char*)d_ws;
  size_t off = 0;
  auto alloc = [&](size_t bytes)->char*{
    char* p = wsb + off; off += (bytes + 255) & ~(size_t)255; return p;
  };
  float* Pg   = (float*)alloc(NREL*DIM*4);
  float* A1LT = (float*)alloc(DIM*DIM*4);
  unsigned short* A2f = (unsigned short*)alloc(2048*8*2);
  unsigned short* WxF = (unsigned short*)alloc((size_t)8192*8*2);
  unsigned short* W1F = (unsigned short*)alloc((size_t)8192*8*2);
  unsigned short* W2F = (unsigned short*)alloc((size_t)8192*8*2);
  float* scaleTab = (float*)alloc((size_t)NENT*4);
  float* Hb = (float*)alloc((size_t)NB*DIM*4);
  float* S1 = (float*)alloc((size_t)NB*DIM*4);
  float* SC = (float*)alloc((size_t)NB*64*4);
  float* SV = (float*)alloc((size_t)NB*2*DIM*4);
  int* E1 = (int*)alloc((size_t)NB*16*4);
  int* R0 = (int*)alloc((size_t)NB*16*4);
  int* E2 = (int*)alloc((size_t)NB*256*4);
  int* R1 = (int*)alloc((size_t)NB*256*4);

  k_prep <<<dim3(384),   dim3(128), 0, stream>>>(rel, A1, A2, Wxw, W1w, W2w,
                                                 Pg, A1LT, A2f, WxF, W1F, W2F);
  k_scale<<<dim3(25000), dim3(256), 0, stream>>>(ent, scaleTab);
  k_gather<<<dim3(NB),   dim3(256), 0, stream>>>(eidx, adjE, adjR, ent, scaleTab,
                                                 E1, R0, E2, R1, Hb, S1, out);
  k_scores<<<dim3(NB),   dim3(256), 0, stream>>>(Hb, S1, A1LT, Pg, A2f, A3, SC);
  k_soft_sv<<<dim3(NB),  dim3(256), 0, stream>>>(E1, R0, E2, R1, SC, ent, scaleTab, SV);
  k_vagg2<<<dim3(NB/32, 2), dim3(256), 0, stream>>>(SV, Hb, S1, WxF, Wxb,
                                                    W1F, W1b, W2F, W2b, out);
}

// Round 6
// 105.127 us; speedup vs baseline: 1.3929x; 1.1146x over previous
//
#include <hip/hip_runtime.h>

#define NENT 100000
#define NREL 32
#define DIM  128
#define NB   2048

typedef short s8v __attribute__((ext_vector_type(8)));
typedef float f4v __attribute__((ext_vector_type(4)));

__device__ __forceinline__ unsigned short f2bf(float x){
  unsigned u = __float_as_uint(x);
  return (unsigned short)((u + 0x7fffu + ((u>>16)&1u)) >> 16);
}
__device__ __forceinline__ float bf2f(unsigned short u){
  return __uint_as_float(((unsigned)u) << 16);
}
__device__ __forceinline__ float lo2f(unsigned p){ return __uint_as_float(p << 16); }
__device__ __forceinline__ float hi2f(unsigned p){ return __uint_as_float(p & 0xffff0000u); }
__device__ __forceinline__ float leakyf(float x){ return x > 0.f ? x : 0.2f*x; }

// ---------------- prep: P[r]; A1LT; A2 frags; Wx/W1/W2 bf16 B-fragment prepack
__global__ __launch_bounds__(128) void k_prep(const float* __restrict__ rel,
                                              const float* __restrict__ A1,
                                              const float* __restrict__ A2,
                                              const float* __restrict__ Wxw,
                                              const float* __restrict__ W1w,
                                              const float* __restrict__ W2w,
                                              float* __restrict__ Pg,
                                              float* __restrict__ A1LT,
                                              unsigned short* __restrict__ A2f,
                                              unsigned short* __restrict__ WxF,
                                              unsigned short* __restrict__ W1F,
                                              unsigned short* __restrict__ W2F){
  int blk = blockIdx.x, t = threadIdx.x;
  if (blk < 32){
    int r = blk;
    __shared__ float srn[128];
    __shared__ float red[2];
    float v = rel[r*128 + t];
    float ss = v*v;
    for (int m=1;m<64;m<<=1) ss += __shfl_xor(ss, m);
    if ((t&63)==0) red[t>>6] = ss;
    __syncthreads();
    float nrm = sqrtf(red[0]+red[1]);
    float f = fminf(1.f, 1.f/(nrm + 1e-7f));
    srn[t] = v*f;
    __syncthreads();
    const float4* ar = (const float4*)(A1 + t*256 + 128);
    float acc = 0.f;
#pragma unroll
    for (int k4=0;k4<32;k4++){
      float4 a = ar[k4];
      acc += a.x*srn[k4*4] + a.y*srn[k4*4+1] + a.z*srn[k4*4+2] + a.w*srn[k4*4+3];
    }
    Pg[r*128 + t] = acc;
  } else if (blk < 64){
    int bb = blk - 32;
    int fid = bb*64 + (t>>1);
    int half = t&1;
    int lane = fid & 63, kc = (fid>>6)&3, dt = fid>>8;
    int d = dt*16 + (lane&15);
    int kb = kc*32 + ((lane>>4)&3)*8 + half*4;
#pragma unroll
    for (int i=0;i<4;i++)
      A2f[fid*8 + half*4 + i] = f2bf(A2[d*128 + kb + i]);
  } else if (blk < 192){
    int kb = blk - 64;          // 0..127
    A1LT[kb*128 + t] = A1[t*256 + kb];
  } else if (blk < 256){
    int fid = (blk-192)*128 + t;
    int l = fid&63, kc = (fid>>6)&3, nt = (fid>>8)&15, iter = (fid>>12)&1;
    int n = nt*16 + (l&15);
    int k = kc*32 + ((l>>4)&3)*8;
    const float* src = Wxw + ((size_t)((iter*2 + (n>>7))*128 + (n&127)))*128 + k;
#pragma unroll
    for (int j=0;j<8;j++) WxF[(size_t)fid*8 + j] = f2bf(src[j]);
  } else if (blk < 320){
    int fid = (blk-256)*128 + t;
    int l = fid&63, kc = (fid>>6)&7, nt = (fid>>9)&15;
    int n = nt*16 + (l&15);
    int k = kc*32 + ((l>>4)&3)*8;
#pragma unroll
    for (int j=0;j<8;j++) W1F[(size_t)fid*8 + j] = f2bf(W1w[(size_t)n*256 + k + j]);
  } else {
    int fid = (blk-320)*128 + t;
    int l = fid&63, kc = (fid>>6)&7, nt = (fid>>9)&15;
    int n = nt*16 + (l&15);
    int k = kc*32 + ((l>>4)&3)*8;
#pragma unroll
    for (int j=0;j<8;j++) W2F[(size_t)fid*8 + j] = f2bf(W2w[(size_t)n*256 + k + j]);
  }
}

// ---------------- per-entity renorm, pre-scaled bf16 table (lane packs 2 dims into 4B)
__global__ __launch_bounds__(256) void k_scale2(const float* __restrict__ ent,
                                                unsigned* __restrict__ entB){
  int row = blockIdx.x*4 + (threadIdx.x>>6);
  if (row >= NENT) return;
  int l = threadIdx.x & 63;
  float2 v = *(const float2*)(ent + (size_t)row*128 + 2*l);
  float ss = v.x*v.x + v.y*v.y;
  for (int m=1;m<64;m<<=1) ss += __shfl_xor(ss, m);
  float sc = fminf(1.f, 1.f/(sqrtf(ss) + 1e-7f));
  entB[(size_t)row*64 + l] = (unsigned)f2bf(sc*v.x) | ((unsigned)f2bf(sc*v.y) << 16);
}

// ---------------- fused per-b: gather + scores + softmax + weighted sums
__global__ __launch_bounds__(256) void k_main(const int* __restrict__ eidx,
                                              const int* __restrict__ adjE,
                                              const int* __restrict__ adjR,
                                              const unsigned* __restrict__ entB,
                                              const float* __restrict__ A1LT,
                                              const float* __restrict__ Pg,
                                              const unsigned short* __restrict__ A2f,
                                              const float* __restrict__ A3,
                                              float* __restrict__ Hb, float* __restrict__ S1,
                                              float* __restrict__ SV,
                                              float* __restrict__ out){
  int b = blockIdx.x, t = threadIdx.x, l = t&63, w = t>>6;
  __shared__ int sE1[16];
  __shared__ int sR0[16];
  __shared__ int sE2[256];
  __shared__ int sR1[256];
  __shared__ unsigned sT1[16*64];        // t1 rows, bf16x2 packed
  __shared__ float sPart[4][128];
  __shared__ float sHS[2][128];
  __shared__ float sC[2][128];
  __shared__ float sP[32][130];
  __shared__ __align__(16) unsigned short sA1b[64*128];
  __shared__ float sSC[64];
  __shared__ float sW0[16];
  __shared__ float sW1[256];
  __shared__ float sRed[4];

  int idx = eidx[b];
  // ---- phase A: indices + t1 stage + h + s1
  if (t < 16){
    int e = adjE[idx*16 + t];
    sE1[t] = e;
    sR0[t] = adjR[idx*16 + t];
  }
  __syncthreads();
  {
    int e1 = sE1[t>>4];
    sE2[t] = adjE[e1*16 + (t&15)];
    sR1[t] = adjR[e1*16 + (t&15)];
  }
  float2 acc = {0.f, 0.f};
#pragma unroll
  for (int i=0;i<4;i++){
    int row = w*4 + i; int e = sE1[row];
    unsigned pk = entB[(size_t)e*64 + l];
    sT1[row*64 + l] = pk;
    acc.x += lo2f(pk); acc.y += hi2f(pk);
  }
  sPart[w][2*l] = acc.x; sPart[w][2*l+1] = acc.y;
  if (w == 0){
    unsigned pk = entB[(size_t)idx*64 + l];
    float2 hv = { lo2f(pk), hi2f(pk) };
    sHS[0][2*l] = hv.x; sHS[0][2*l+1] = hv.y;
    *(float2*)(Hb + b*128 + 2*l) = hv;
    *(float2*)(out + (size_t)b*640 + 512 + 2*l) = hv;
  }
  __syncthreads();
  if (t < 128){
    float s = sPart[0][t]+sPart[1][t]+sPart[2][t]+sPart[3][t];
    sHS[1][t] = s;
    S1[b*128 + t] = s;
  }
#pragma unroll
  for (int i=0;i<16;i++){ int id = i*256 + t; sP[id>>7][id&127] = Pg[id]; }
  __syncthreads();

  // ---- phase B: scores
  { // c0/c1 matvec
    int i = t>>7, d = t&127;
    float a0 = 0.f;
#pragma unroll 4
    for (int k=0;k<128;k++) a0 += A1LT[k*128 + d] * sHS[i][k];
    sC[i][d] = a0;
  }
  __syncthreads();
  { // build a1 bf16, swizzled
    int c = t & 63, i = c>>5, r = c&31, base = t>>6;
#pragma unroll
    for (int ch=0; ch<16; ch++){
      int kp = base*16 + ch;
      float2 cc = *(const float2*)&sC[i][2*kp];
      float2 pp = *(const float2*)&sP[r][2*kp];
      float v0 = fmaxf(cc.x + pp.x, 0.f);
      float v1 = fmaxf(cc.y + pp.y, 0.f);
      unsigned pk = (unsigned)f2bf(v0) | ((unsigned)f2bf(v1) << 16);
      int byte = (c*256 + kp*4) ^ ((c&7)<<4);
      *(unsigned*)((char*)sA1b + byte) = pk;
    }
  }
  __syncthreads();
  { // MFMA + A3 fold + sigmoid -> sSC
    int c0 = w*16, cl = l & 15, kg = l >> 4;
    int c = c0 + cl;
    s8v bfrag[4];
#pragma unroll
    for (int kc=0;kc<4;kc++){
      int byte = (c*256 + kc*64 + kg*16) ^ ((c&7)<<4);
      bfrag[kc] = *(const s8v*)((const char*)sA1b + byte);
    }
    float sacc = 0.f;
#pragma unroll
    for (int dt=0; dt<8; dt++){
      f4v a4 = {0.f,0.f,0.f,0.f};
#pragma unroll
      for (int kc=0;kc<4;kc++){
        s8v af = *(const s8v*)(A2f + ((size_t)((dt*4+kc)*64 + l))*8);
        a4 = __builtin_amdgcn_mfma_f32_16x16x32_bf16(af, bfrag[kc], a4, 0, 0, 0);
      }
      float4 a3v = *(const float4*)(A3 + dt*16 + kg*4);
      sacc += fmaxf(a4[0],0.f)*a3v.x + fmaxf(a4[1],0.f)*a3v.y
            + fmaxf(a4[2],0.f)*a3v.z + fmaxf(a4[3],0.f)*a3v.w;
    }
    sacc += __shfl_xor(sacc, 16);
    sacc += __shfl_xor(sacc, 32);
    if (l < 16) sSC[c0 + l] = 1.f/(1.f + __expf(-sacc));
  }
  __syncthreads();

  // ---- phase C: softmax weights + weighted gathers
  float ev = __expf(sSC[32 + sR1[t]]);
  float ssum = ev;
  for (int m=1;m<64;m<<=1) ssum += __shfl_xor(ssum, m);
  if (l==0) sRed[w] = ssum;
  if (t < 16){
    float e0 = __expf(sSC[sR0[t]]);
    float s0 = e0;
    for (int m=1;m<16;m<<=1) s0 += __shfl_xor(s0, m, 16);
    sW0[t] = e0/s0;
  }
  __syncthreads();
  float tot = sRed[0]+sRed[1]+sRed[2]+sRed[3];
  sW1[t] = ev / tot;
  __syncthreads();

  float2 a0 = {0.f,0.f};
#pragma unroll
  for (int i=0;i<4;i++){
    int row = w*4 + i;
    float f = sW0[row];
    unsigned pk = sT1[row*64 + l];
    a0.x += f*lo2f(pk); a0.y += f*hi2f(pk);
  }
  float2 a1 = {0.f,0.f};
#pragma unroll 4
  for (int i=0;i<64;i++){
    int row = w*64 + i; int e = sE2[row];
    float f = sW1[row];
    unsigned pk = entB[(size_t)e*64 + l];
    a1.x += f*lo2f(pk); a1.y += f*hi2f(pk);
  }
  *(float2*)&sPart[w][2*l] = a0;
  __syncthreads();
  if (t < 128) SV[((size_t)b*2 + 0)*128 + t] = sPart[0][t]+sPart[1][t]+sPart[2][t]+sPart[3][t];
  __syncthreads();
  *(float2*)&sPart[w][2*l] = a1;
  __syncthreads();
  if (t < 128) SV[((size_t)b*2 + 1)*128 + t] = sPart[0][t]+sPart[1][t]+sPart[2][t]+sPart[3][t];
}

// ---------------- MFMA vagg: G1 V=leaky(Wx@sv+b) ; G2 e=leaky(W1@x1+b1)+leaky(W2@x2+b2)
__global__ __launch_bounds__(256) void k_vagg2(const float* __restrict__ SV,
                                               const float* __restrict__ Hb,
                                               const float* __restrict__ S1,
                                               const unsigned short* __restrict__ WxF,
                                               const float* __restrict__ Wxb,
                                               const unsigned short* __restrict__ W1F,
                                               const float* __restrict__ W1b,
                                               const unsigned short* __restrict__ W2F,
                                               const float* __restrict__ W2b,
                                               float* __restrict__ out){
  int b0 = blockIdx.x * 32;
  int iter = blockIdx.y;
  int t = threadIdx.x, l = t&63, w = t>>6;
  int wm = w>>1, wn = w&1;
  __shared__ __align__(16) unsigned short sSV[32*128];
  __shared__ __align__(16) unsigned short sA [32*128];
  __shared__ __align__(16) unsigned short sV [32*256];
  char* sSVb = (char*)sSV; char* sAb = (char*)sA; char* sVb = (char*)sV;

  const float* anc = iter ? S1 : Hb;
  {
    int row = t>>3, c0 = (t&7)*16;
    const float* ps = SV + ((size_t)(b0+row)*2 + iter)*128 + c0;
    const float* pa = anc + (size_t)(b0+row)*128 + c0;
    int xo = (row&7)<<4;
#pragma unroll
    for (int c2=0;c2<8;c2++){
      float2 sv2 = *(const float2*)(ps + c2*2);
      float2 an2 = *(const float2*)(pa + c2*2);
      unsigned pv  = (unsigned)f2bf(sv2.x) | ((unsigned)f2bf(sv2.y)<<16);
      unsigned pan = (unsigned)f2bf(an2.x) | ((unsigned)f2bf(an2.y)<<16);
      int byte = (row*256 + c0*2 + c2*4) ^ xo;
      *(unsigned*)(sSVb + byte) = pv;
      *(unsigned*)(sAb  + byte) = pan;
    }
  }
  __syncthreads();

  int kl = l&15, kg = l>>4;
  {
    int rowg = wm*16 + kl;
    int xo = (rowg&7)<<4;
    s8v af[4];
#pragma unroll
    for (int kc=0;kc<4;kc++)
      af[kc] = *(const s8v*)(sSVb + ((rowg*256 + kc*64 + kg*16) ^ xo));
#pragma unroll
    for (int nt8=0;nt8<8;nt8++){
      int ntg = wn*8 + nt8;
      int n = ntg*16 + kl;
      float bias = Wxb[iter*256 + n];
      f4v acc = {bias,bias,bias,bias};
#pragma unroll
      for (int kc=0;kc<4;kc++){
        s8v bf = *(const s8v*)(WxF + ((size_t)(((iter*16 + ntg)*4 + kc)*64 + l))*8);
        acc = __builtin_amdgcn_mfma_f32_16x16x32_bf16(af[kc], bf, acc, 0, 0, 0);
      }
#pragma unroll
      for (int r=0;r<4;r++){
        int rowl = wm*16 + kg*4 + r;
        int byte = (rowl*512 + n*2) ^ ((rowl&7)<<4);
        *(unsigned short*)(sVb + byte) = f2bf(leakyf(acc[r]));
      }
    }
  }
  __syncthreads();
  {
    int rowl = wm*16 + kl;
    int xo = (rowl&7)<<4;
    s8v x1f[8], x2f[8];
#pragma unroll
    for (int kc=0;kc<8;kc++){
      int k0 = kc*32 + kg*8;
      s8v vv = *(const s8v*)(sVb + ((rowl*512 + k0*2) ^ xo));
      s8v aa = *(const s8v*)(sAb + ((rowl*256 + (k0&127)*2) ^ xo));
#pragma unroll
      for (int j=0;j<8;j++){
        float vf = bf2f((unsigned short)vv[j]);
        float av = bf2f((unsigned short)aa[j]);
        x1f[kc][j] = (short)f2bf(av + vf);
        x2f[kc][j] = (short)f2bf(av * vf);
      }
    }
    int obase = iter ? 0 : 256;
#pragma unroll
    for (int nt8=0;nt8<8;nt8++){
      int ntg = wn*8 + nt8;
      int n = ntg*16 + kl;
      float bb1 = W1b[n], bb2 = W2b[n];
      f4v a1 = {bb1,bb1,bb1,bb1};
      f4v a2 = {bb2,bb2,bb2,bb2};
#pragma unroll
      for (int kc=0;kc<8;kc++){
        s8v wf1 = *(const s8v*)(W1F + ((size_t)((ntg*8 + kc)*64 + l))*8);
        a1 = __builtin_amdgcn_mfma_f32_16x16x32_bf16(x1f[kc], wf1, a1, 0, 0, 0);
      }
#pragma unroll
      for (int kc=0;kc<8;kc++){
        s8v wf2 = *(const s8v*)(W2F + ((size_t)((ntg*8 + kc)*64 + l))*8);
        a2 = __builtin_amdgcn_mfma_f32_16x16x32_bf16(x2f[kc], wf2, a2, 0, 0, 0);
      }
#pragma unroll
      for (int r=0;r<4;r++){
        int row = wm*16 + kg*4 + r;
        out[(size_t)(b0+row)*640 + obase + n] = leakyf(a1[r]) + leakyf(a2[r]);
      }
    }
  }
}

extern "C" void kernel_launch(void* const* d_in, const int* in_sizes, int n_in,
                              void* d_out, int out_size, void* d_ws, size_t ws_size,
                              hipStream_t stream) {
  const int*   eidx = (const int*)d_in[0];
  const int*   adjE = (const int*)d_in[1];
  const int*   adjR = (const int*)d_in[2];
  const float* ent  = (const float*)d_in[3];
  const float* rel  = (const float*)d_in[4];
  const float* A1   = (const float*)d_in[5];
  const float* A2   = (const float*)d_in[6];
  const float* A3   = (const float*)d_in[7];
  const float* Wxw  = (const float*)d_in[8];
  const float* Wxb  = (const float*)d_in[9];
  const float* W1w  = (const float*)d_in[10];
  const float* W1b  = (const float*)d_in[11];
  const float* W2w  = (const float*)d_in[12];
  const float* W2b  = (const float*)d_in[13];
  float* out = (float*)d_out;

  char* wsb = (char*)d_ws;
  size_t off = 0;
  auto alloc = [&](size_t bytes)->char*{
    char* p = wsb + off; off += (bytes + 255) & ~(size_t)255; return p;
  };
  float* Pg   = (float*)alloc(NREL*DIM*4);
  float* A1LT = (float*)alloc(DIM*DIM*4);
  unsigned short* A2f = (unsigned short*)alloc(2048*8*2);
  unsigned short* WxF = (unsigned short*)alloc((size_t)8192*8*2);
  unsigned short* W1F = (unsigned short*)alloc((size_t)8192*8*2);
  unsigned short* W2F = (unsigned short*)alloc((size_t)8192*8*2);
  unsigned* entB = (unsigned*)alloc((size_t)NENT*64*4);
  float* Hb = (float*)alloc((size_t)NB*DIM*4);
  float* S1 = (float*)alloc((size_t)NB*DIM*4);
  float* SV = (float*)alloc((size_t)NB*2*DIM*4);

  k_prep <<<dim3(384),   dim3(128), 0, stream>>>(rel, A1, A2, Wxw, W1w, W2w,
                                                 Pg, A1LT, A2f, WxF, W1F, W2F);
  k_scale2<<<dim3(25000), dim3(256), 0, stream>>>(ent, entB);
  k_main<<<dim3(NB),     dim3(256), 0, stream>>>(eidx, adjE, adjR, entB,
                                                 A1LT, Pg, A2f, A3, Hb, S1, SV, out);
  k_vagg2<<<dim3(NB/32, 2), dim3(256), 0, stream>>>(SV, Hb, S1, WxF, Wxb,
                                                    W1F, W1b, W2F, W2b, out);
}

// Round 7
// 95.016 us; speedup vs baseline: 1.5411x; 1.1064x over previous
//
#include <hip/hip_runtime.h>

#define NENT 100000
#define NREL 32
#define DIM  128
#define NB   2048

typedef short s8v __attribute__((ext_vector_type(8)));
typedef float f4v __attribute__((ext_vector_type(4)));

__device__ __forceinline__ unsigned short f2bf(float x){
  unsigned u = __float_as_uint(x);
  return (unsigned short)((u + 0x7fffu + ((u>>16)&1u)) >> 16);
}
__device__ __forceinline__ float bf2f(unsigned short u){
  return __uint_as_float(((unsigned)u) << 16);
}
__device__ __forceinline__ float lo2f(unsigned p){ return __uint_as_float(p << 16); }
__device__ __forceinline__ float hi2f(unsigned p){ return __uint_as_float(p & 0xffff0000u); }
__device__ __forceinline__ float leakyf(float x){ return x > 0.f ? x : 0.2f*x; }

// ---------------- prep: P[r]; A1LT; A2 frags; Wx/W1/W2 bf16 B-fragment prepack
__global__ __launch_bounds__(128) void k_prep(const float* __restrict__ rel,
                                              const float* __restrict__ A1,
                                              const float* __restrict__ A2,
                                              const float* __restrict__ Wxw,
                                              const float* __restrict__ W1w,
                                              const float* __restrict__ W2w,
                                              float* __restrict__ Pg,
                                              float* __restrict__ A1LT,
                                              unsigned short* __restrict__ A2f,
                                              unsigned short* __restrict__ WxF,
                                              unsigned short* __restrict__ W1F,
                                              unsigned short* __restrict__ W2F){
  int blk = blockIdx.x, t = threadIdx.x;
  if (blk < 32){
    int r = blk;
    __shared__ float srn[128];
    __shared__ float red[2];
    float v = rel[r*128 + t];
    float ss = v*v;
    for (int m=1;m<64;m<<=1) ss += __shfl_xor(ss, m);
    if ((t&63)==0) red[t>>6] = ss;
    __syncthreads();
    float nrm = sqrtf(red[0]+red[1]);
    float f = fminf(1.f, 1.f/(nrm + 1e-7f));
    srn[t] = v*f;
    __syncthreads();
    const float4* ar = (const float4*)(A1 + t*256 + 128);
    float acc = 0.f;
#pragma unroll
    for (int k4=0;k4<32;k4++){
      float4 a = ar[k4];
      acc += a.x*srn[k4*4] + a.y*srn[k4*4+1] + a.z*srn[k4*4+2] + a.w*srn[k4*4+3];
    }
    Pg[r*128 + t] = acc;
  } else if (blk < 64){
    int bb = blk - 32;
    int fid = bb*64 + (t>>1);
    int half = t&1;
    int lane = fid & 63, kc = (fid>>6)&3, dt = fid>>8;
    int d = dt*16 + (lane&15);
    int kb = kc*32 + ((lane>>4)&3)*8 + half*4;
#pragma unroll
    for (int i=0;i<4;i++)
      A2f[fid*8 + half*4 + i] = f2bf(A2[d*128 + kb + i]);
  } else if (blk < 192){
    int kb = blk - 64;          // 0..127
    A1LT[kb*128 + t] = A1[t*256 + kb];
  } else if (blk < 256){
    int fid = (blk-192)*128 + t;
    int l = fid&63, kc = (fid>>6)&3, nt = (fid>>8)&15, iter = (fid>>12)&1;
    int n = nt*16 + (l&15);
    int k = kc*32 + ((l>>4)&3)*8;
    const float* src = Wxw + ((size_t)((iter*2 + (n>>7))*128 + (n&127)))*128 + k;
#pragma unroll
    for (int j=0;j<8;j++) WxF[(size_t)fid*8 + j] = f2bf(src[j]);
  } else if (blk < 320){
    int fid = (blk-256)*128 + t;
    int l = fid&63, kc = (fid>>6)&7, nt = (fid>>9)&15;
    int n = nt*16 + (l&15);
    int k = kc*32 + ((l>>4)&3)*8;
#pragma unroll
    for (int j=0;j<8;j++) W1F[(size_t)fid*8 + j] = f2bf(W1w[(size_t)n*256 + k + j]);
  } else {
    int fid = (blk-320)*128 + t;
    int l = fid&63, kc = (fid>>6)&7, nt = (fid>>9)&15;
    int n = nt*16 + (l&15);
    int k = kc*32 + ((l>>4)&3)*8;
#pragma unroll
    for (int j=0;j<8;j++) W2F[(size_t)fid*8 + j] = f2bf(W2w[(size_t)n*256 + k + j]);
  }
}

// ---------------- per-entity renorm, pre-scaled bf16 table (lane packs 2 dims into 4B)
__global__ __launch_bounds__(256) void k_scale2(const float* __restrict__ ent,
                                                unsigned* __restrict__ entB){
  int row = blockIdx.x*4 + (threadIdx.x>>6);
  if (row >= NENT) return;
  int l = threadIdx.x & 63;
  float2 v = *(const float2*)(ent + (size_t)row*128 + 2*l);
  float ss = v.x*v.x + v.y*v.y;
  for (int m=1;m<64;m<<=1) ss += __shfl_xor(ss, m);
  float sc = fminf(1.f, 1.f/(sqrtf(ss) + 1e-7f));
  entB[(size_t)row*64 + l] = (unsigned)f2bf(sc*v.x) | ((unsigned)f2bf(sc*v.y) << 16);
}

// ---------------- per-b: indices + h/s1 + scores (in-reg B-frags) + softmax weights
__global__ __launch_bounds__(256) void k_attn(const int* __restrict__ eidx,
                                              const int* __restrict__ adjE,
                                              const int* __restrict__ adjR,
                                              const unsigned* __restrict__ entB,
                                              const float* __restrict__ A1LT,
                                              const float* __restrict__ Pg,
                                              const unsigned short* __restrict__ A2f,
                                              const float* __restrict__ A3,
                                              int* __restrict__ E1g, int* __restrict__ E2g,
                                              float* __restrict__ W0g, float* __restrict__ W1g,
                                              float* __restrict__ Hb, float* __restrict__ S1,
                                              float* __restrict__ out){
  int b = blockIdx.x, t = threadIdx.x, l = t&63, w = t>>6;
  __shared__ int sE1[16];
  __shared__ int sR0[16];
  __shared__ int sR1[256];
  __shared__ float sPart[4][128];
  __shared__ float sHS[2][128];
  __shared__ float sC[2][128];
  __shared__ float sSC[64];
  __shared__ float sRed[4];

  int idx = eidx[b];
  if (t < 16){
    int e = adjE[idx*16 + t];
    sE1[t] = e; E1g[b*16+t] = e;
    sR0[t] = adjR[idx*16 + t];
  }
  __syncthreads();
  {
    int e1 = sE1[t>>4];
    E2g[b*256+t] = adjE[e1*16 + (t&15)];
    sR1[t] = adjR[e1*16 + (t&15)];
  }
  float2 acc = {0.f, 0.f};
#pragma unroll
  for (int i=0;i<4;i++){
    int row = w*4 + i; int e = sE1[row];
    unsigned pk = entB[(size_t)e*64 + l];
    acc.x += lo2f(pk); acc.y += hi2f(pk);
  }
  sPart[w][2*l] = acc.x; sPart[w][2*l+1] = acc.y;
  if (w == 0){
    unsigned pk = entB[(size_t)idx*64 + l];
    float2 hv = { lo2f(pk), hi2f(pk) };
    sHS[0][2*l] = hv.x; sHS[0][2*l+1] = hv.y;
    *(float2*)(Hb + b*128 + 2*l) = hv;
    *(float2*)(out + (size_t)b*640 + 512 + 2*l) = hv;
  }
  __syncthreads();
  if (t < 128){
    float s = sPart[0][t]+sPart[1][t]+sPart[2][t]+sPart[3][t];
    sHS[1][t] = s;
    S1[b*128 + t] = s;
  }
  __syncthreads();

  { // c0/c1 matvec
    int i = t>>7, d = t&127;
    float a0 = 0.f;
#pragma unroll 4
    for (int k=0;k<128;k++) a0 += A1LT[k*128 + d] * sHS[i][k];
    sC[i][d] = a0;
  }
  __syncthreads();

  { // scores: B-frags computed in-register; MFMA vs prepacked A2 frags; A3 fold; sigmoid
    int c0 = w*16, cl = l & 15, kg = l >> 4;
    int c = c0 + cl;
    int ci = c>>5, r = c&31;
    s8v bfrag[4];
#pragma unroll
    for (int kc=0;kc<4;kc++){
      int k0 = kc*32 + kg*8;
      float4 ca = *(const float4*)&sC[ci][k0];
      float4 cb = *(const float4*)&sC[ci][k0+4];
      float4 pa = *(const float4*)(Pg + r*128 + k0);
      float4 pb = *(const float4*)(Pg + r*128 + k0 + 4);
      bfrag[kc][0] = (short)f2bf(fmaxf(ca.x+pa.x, 0.f));
      bfrag[kc][1] = (short)f2bf(fmaxf(ca.y+pa.y, 0.f));
      bfrag[kc][2] = (short)f2bf(fmaxf(ca.z+pa.z, 0.f));
      bfrag[kc][3] = (short)f2bf(fmaxf(ca.w+pa.w, 0.f));
      bfrag[kc][4] = (short)f2bf(fmaxf(cb.x+pb.x, 0.f));
      bfrag[kc][5] = (short)f2bf(fmaxf(cb.y+pb.y, 0.f));
      bfrag[kc][6] = (short)f2bf(fmaxf(cb.z+pb.z, 0.f));
      bfrag[kc][7] = (short)f2bf(fmaxf(cb.w+pb.w, 0.f));
    }
    float sacc = 0.f;
#pragma unroll
    for (int dt=0; dt<8; dt++){
      f4v a4 = {0.f,0.f,0.f,0.f};
#pragma unroll
      for (int kc=0;kc<4;kc++){
        s8v af = *(const s8v*)(A2f + ((size_t)((dt*4+kc)*64 + l))*8);
        a4 = __builtin_amdgcn_mfma_f32_16x16x32_bf16(af, bfrag[kc], a4, 0, 0, 0);
      }
      float4 a3v = *(const float4*)(A3 + dt*16 + kg*4);
      sacc += fmaxf(a4[0],0.f)*a3v.x + fmaxf(a4[1],0.f)*a3v.y
            + fmaxf(a4[2],0.f)*a3v.z + fmaxf(a4[3],0.f)*a3v.w;
    }
    sacc += __shfl_xor(sacc, 16);
    sacc += __shfl_xor(sacc, 32);
    if (l < 16) sSC[c0 + l] = 1.f/(1.f + __expf(-sacc));
  }
  __syncthreads();

  // softmax weights
  float ev = __expf(sSC[32 + sR1[t]]);
  float ssum = ev;
  for (int m=1;m<64;m<<=1) ssum += __shfl_xor(ssum, m);
  if (l==0) sRed[w] = ssum;
  if (t < 16){
    float e0 = __expf(sSC[sR0[t]]);
    float s0 = e0;
    for (int m=1;m<16;m<<=1) s0 += __shfl_xor(s0, m, 16);
    W0g[b*16 + t] = e0/s0;
  }
  __syncthreads();
  float tot = sRed[0]+sRed[1]+sRed[2]+sRed[3];
  W1g[b*256 + t] = ev / tot;
}

// ---------------- weighted gathers (bf16 entB, precomputed weights) -> SV
__global__ __launch_bounds__(256) void k_sv2(const int* __restrict__ E1g,
                                             const int* __restrict__ E2g,
                                             const float* __restrict__ W0g,
                                             const float* __restrict__ W1g,
                                             const unsigned* __restrict__ entB,
                                             float* __restrict__ SV){
  int b = blockIdx.x, t = threadIdx.x, l = t&63, w = t>>6;
  __shared__ float sW0[16];
  __shared__ float sW1[256];
  __shared__ int sE1[16];
  __shared__ int sE2[256];
  __shared__ float sPart[4][128];
  if (t < 16){ sE1[t] = E1g[b*16+t]; sW0[t] = W0g[b*16+t]; }
  sE2[t] = E2g[b*256+t];
  sW1[t] = W1g[b*256+t];
  __syncthreads();

  float2 a0 = {0.f,0.f};
#pragma unroll
  for (int i=0;i<4;i++){
    int row = w*4 + i;
    float f = sW0[row];
    unsigned pk = entB[(size_t)sE1[row]*64 + l];
    a0.x += f*lo2f(pk); a0.y += f*hi2f(pk);
  }
  float2 a1 = {0.f,0.f};
#pragma unroll 4
  for (int i=0;i<64;i++){
    int row = w*64 + i;
    float f = sW1[row];
    unsigned pk = entB[(size_t)sE2[row]*64 + l];
    a1.x += f*lo2f(pk); a1.y += f*hi2f(pk);
  }
  *(float2*)&sPart[w][2*l] = a0;
  __syncthreads();
  if (t < 128) SV[((size_t)b*2 + 0)*128 + t] = sPart[0][t]+sPart[1][t]+sPart[2][t]+sPart[3][t];
  __syncthreads();
  *(float2*)&sPart[w][2*l] = a1;
  __syncthreads();
  if (t < 128) SV[((size_t)b*2 + 1)*128 + t] = sPart[0][t]+sPart[1][t]+sPart[2][t]+sPart[3][t];
}

// ---------------- MFMA vagg: G1 V=leaky(Wx@sv+b) ; G2 e=leaky(W1@x1+b1)+leaky(W2@x2+b2)
__global__ __launch_bounds__(256) void k_vagg2(const float* __restrict__ SV,
                                               const float* __restrict__ Hb,
                                               const float* __restrict__ S1,
                                               const unsigned short* __restrict__ WxF,
                                               const float* __restrict__ Wxb,
                                               const unsigned short* __restrict__ W1F,
                                               const float* __restrict__ W1b,
                                               const unsigned short* __restrict__ W2F,
                                               const float* __restrict__ W2b,
                                               float* __restrict__ out){
  int b0 = blockIdx.x * 32;
  int iter = blockIdx.y;
  int t = threadIdx.x, l = t&63, w = t>>6;
  int wm = w>>1, wn = w&1;
  __shared__ __align__(16) unsigned short sSV[32*128];
  __shared__ __align__(16) unsigned short sA [32*128];
  __shared__ __align__(16) unsigned short sV [32*256];
  char* sSVb = (char*)sSV; char* sAb = (char*)sA; char* sVb = (char*)sV;

  const float* anc = iter ? S1 : Hb;
  {
    int row = t>>3, c0 = (t&7)*16;
    const float* ps = SV + ((size_t)(b0+row)*2 + iter)*128 + c0;
    const float* pa = anc + (size_t)(b0+row)*128 + c0;
    int xo = (row&7)<<4;
#pragma unroll
    for (int c2=0;c2<8;c2++){
      float2 sv2 = *(const float2*)(ps + c2*2);
      float2 an2 = *(const float2*)(pa + c2*2);
      unsigned pv  = (unsigned)f2bf(sv2.x) | ((unsigned)f2bf(sv2.y)<<16);
      unsigned pan = (unsigned)f2bf(an2.x) | ((unsigned)f2bf(an2.y)<<16);
      int byte = (row*256 + c0*2 + c2*4) ^ xo;
      *(unsigned*)(sSVb + byte) = pv;
      *(unsigned*)(sAb  + byte) = pan;
    }
  }
  __syncthreads();

  int kl = l&15, kg = l>>4;
  {
    int rowg = wm*16 + kl;
    int xo = (rowg&7)<<4;
    s8v af[4];
#pragma unroll
    for (int kc=0;kc<4;kc++)
      af[kc] = *(const s8v*)(sSVb + ((rowg*256 + kc*64 + kg*16) ^ xo));
#pragma unroll
    for (int nt8=0;nt8<8;nt8++){
      int ntg = wn*8 + nt8;
      int n = ntg*16 + kl;
      float bias = Wxb[iter*256 + n];
      f4v acc = {bias,bias,bias,bias};
#pragma unroll
      for (int kc=0;kc<4;kc++){
        s8v bf = *(const s8v*)(WxF + ((size_t)(((iter*16 + ntg)*4 + kc)*64 + l))*8);
        acc = __builtin_amdgcn_mfma_f32_16x16x32_bf16(af[kc], bf, acc, 0, 0, 0);
      }
#pragma unroll
      for (int r=0;r<4;r++){
        int rowl = wm*16 + kg*4 + r;
        int byte = (rowl*512 + n*2) ^ ((rowl&7)<<4);
        *(unsigned short*)(sVb + byte) = f2bf(leakyf(acc[r]));
      }
    }
  }
  __syncthreads();
  {
    int rowl = wm*16 + kl;
    int xo = (rowl&7)<<4;
    s8v x1f[8], x2f[8];
#pragma unroll
    for (int kc=0;kc<8;kc++){
      int k0 = kc*32 + kg*8;
      s8v vv = *(const s8v*)(sVb + ((rowl*512 + k0*2) ^ xo));
      s8v aa = *(const s8v*)(sAb + ((rowl*256 + (k0&127)*2) ^ xo));
#pragma unroll
      for (int j=0;j<8;j++){
        float vf = bf2f((unsigned short)vv[j]);
        float av = bf2f((unsigned short)aa[j]);
        x1f[kc][j] = (short)f2bf(av + vf);
        x2f[kc][j] = (short)f2bf(av * vf);
      }
    }
    int obase = iter ? 0 : 256;
#pragma unroll
    for (int nt8=0;nt8<8;nt8++){
      int ntg = wn*8 + nt8;
      int n = ntg*16 + kl;
      float bb1 = W1b[n], bb2 = W2b[n];
      f4v a1 = {bb1,bb1,bb1,bb1};
      f4v a2 = {bb2,bb2,bb2,bb2};
#pragma unroll
      for (int kc=0;kc<8;kc++){
        s8v wf1 = *(const s8v*)(W1F + ((size_t)((ntg*8 + kc)*64 + l))*8);
        a1 = __builtin_amdgcn_mfma_f32_16x16x32_bf16(x1f[kc], wf1, a1, 0, 0, 0);
      }
#pragma unroll
      for (int kc=0;kc<8;kc++){
        s8v wf2 = *(const s8v*)(W2F + ((size_t)((ntg*8 + kc)*64 + l))*8);
        a2 = __builtin_amdgcn_mfma_f32_16x16x32_bf16(x2f[kc], wf2, a2, 0, 0, 0);
      }
#pragma unroll
      for (int r=0;r<4;r++){
        int row = wm*16 + kg*4 + r;
        out[(size_t)(b0+row)*640 + obase + n] = leakyf(a1[r]) + leakyf(a2[r]);
      }
    }
  }
}

extern "C" void kernel_launch(void* const* d_in, const int* in_sizes, int n_in,
                              void* d_out, int out_size, void* d_ws, size_t ws_size,
                              hipStream_t stream) {
  const int*   eidx = (const int*)d_in[0];
  const int*   adjE = (const int*)d_in[1];
  const int*   adjR = (const int*)d_in[2];
  const float* ent  = (const float*)d_in[3];
  const float* rel  = (const float*)d_in[4];
  const float* A1   = (const float*)d_in[5];
  const float* A2   = (const float*)d_in[6];
  const float* A3   = (const float*)d_in[7];
  const float* Wxw  = (const float*)d_in[8];
  const float* Wxb  = (const float*)d_in[9];
  const float* W1w  = (const float*)d_in[10];
  const float* W1b  = (const float*)d_in[11];
  const float* W2w  = (const float*)d_in[12];
  const float* W2b  = (const float*)d_in[13];
  float* out = (float*)d_out;

  char* wsb = (char*)d_ws;
  size_t off = 0;
  auto alloc = [&](size_t bytes)->char*{
    char* p = wsb + off; off += (bytes + 255) & ~(size_t)255; return p;
  };
  float* Pg   = (float*)alloc(NREL*DIM*4);
  float* A1LT = (float*)alloc(DIM*DIM*4);
  unsigned short* A2f = (unsigned short*)alloc(2048*8*2);
  unsigned short* WxF = (unsigned short*)alloc((size_t)8192*8*2);
  unsigned short* W1F = (unsigned short*)alloc((size_t)8192*8*2);
  unsigned short* W2F = (unsigned short*)alloc((size_t)8192*8*2);
  unsigned* entB = (unsigned*)alloc((size_t)NENT*64*4);
  float* Hb = (float*)alloc((size_t)NB*DIM*4);
  float* S1 = (float*)alloc((size_t)NB*DIM*4);
  float* SV = (float*)alloc((size_t)NB*2*DIM*4);
  int* E1g = (int*)alloc((size_t)NB*16*4);
  int* E2g = (int*)alloc((size_t)NB*256*4);
  float* W0g = (float*)alloc((size_t)NB*16*4);
  float* W1g = (float*)alloc((size_t)NB*256*4);

  k_prep <<<dim3(384),   dim3(128), 0, stream>>>(rel, A1, A2, Wxw, W1w, W2w,
                                                 Pg, A1LT, A2f, WxF, W1F, W2F);
  k_scale2<<<dim3(25000), dim3(256), 0, stream>>>(ent, entB);
  k_attn<<<dim3(NB),     dim3(256), 0, stream>>>(eidx, adjE, adjR, entB,
                                                 A1LT, Pg, A2f, A3,
                                                 E1g, E2g, W0g, W1g, Hb, S1, out);
  k_sv2 <<<dim3(NB),     dim3(256), 0, stream>>>(E1g, E2g, W0g, W1g, entB, SV);
  k_vagg2<<<dim3(NB/32, 2), dim3(256), 0, stream>>>(SV, Hb, S1, WxF, Wxb,
                                                    W1F, W1b, W2F, W2b, out);
}